// Round 8
// baseline (504.087 us; speedup 1.0000x reference)
//
#include <hip/hip_runtime.h>
#include <hip/hip_bf16.h>
#include <math.h>

#define B_ROWS 1024
#define V_COLS 50257
#define E_DIM  128
#define VPAD   50304               // padded V (multiple of 128; 1572*32)
#define NNB4   (VPAD / 4)
#define N4     (V_COLS * E_DIM / 4)   // 1608224
#define N4P    (VPAD * E_DIM / 4)     // 1609728
#define NSTEPS (VPAD / 32)         // 1572 column steps of 32
#define NCH    128                 // column chunks; 16 rowgrps x 128 chunks = 2048 waves

typedef __attribute__((ext_vector_type(8))) short short8;
typedef __attribute__((ext_vector_type(4))) float floatx4;

static __device__ __forceinline__ unsigned short f2bf(float x) {
    union { float f; unsigned int u; } c; c.f = x;
    unsigned int u = c.u;
    unsigned int r = u + 0x7fffu + ((u >> 16) & 1u);
    return (unsigned short)(r >> 16);
}

// ---------------------------------------------------------------- find one-hot index
__global__ void find_idx_kernel(const float* __restrict__ xs, int* __restrict__ idx) {
    long i = (long)blockIdx.x * blockDim.x + threadIdx.x;
    const long n4 = (long)B_ROWS * V_COLS / 4;
    if (i >= n4) return;
    floatx4 v = __builtin_nontemporal_load((const floatx4*)xs + i);
    float vals[4] = {v.x, v.y, v.z, v.w};
    #pragma unroll
    for (int c = 0; c < 4; ++c) {
        if (vals[c] != 0.0f) {
            long f = 4 * i + c;
            int b = (int)(f / V_COLS);
            idx[b] = (int)(f - (long)b * V_COLS);
        }
    }
}

// ---------------------------------------------------------------- NEG fp32 -> bf16 (padded to VPAD rows, zeros)
__global__ void cvt_bf16_kernel(const float* __restrict__ src, ushort4* __restrict__ dst) {
    int i = blockIdx.x * blockDim.x + threadIdx.x;
    if (i >= N4P) return;
    ushort4 o;
    if (i < N4) {
        floatx4 v = __builtin_nontemporal_load((const floatx4*)src + i);
        o.x = f2bf(v.x); o.y = f2bf(v.y); o.z = f2bf(v.z); o.w = f2bf(v.w);
    } else {
        o.x = 0; o.y = 0; o.z = 0; o.w = 0;
    }
    dst[i] = o;
}

// ---------------------------------------------------------------- t[b] = EMBEDM[idx[b]] @ metric  (bf16 out)
__global__ void compute_t_kernel(const float* __restrict__ EMB, const float* __restrict__ metric,
                                 const int* __restrict__ idx, unsigned short* __restrict__ t) {
    __shared__ float erow[E_DIM];
    int b = blockIdx.x, tid = threadIdx.x;
    int id = idx[b];
    erow[tid] = EMB[(long)id * E_DIM + tid];
    __syncthreads();
    float acc = 0.f;
    #pragma unroll 16
    for (int k = 0; k < E_DIM; ++k) acc += erow[k] * metric[k * E_DIM + tid];
    t[b * E_DIM + tid] = f2bf(acc);
}

// ---------------------------------------------------------------- barrier-free register-direct GEMM
// 2048 independent waves (512 blocks x 4 waves, no __syncthreads in loop, no LDS).
// Wave = (rowgrp 0..15, chunk 0..127): 64 rows x ~12 steps of 32 cols.
// A-frags (64 rows x K=128) in registers from L2-hot t; B loaded straight to registers
// from L3-hot neg16, double-buffered in two NAMED register sets (static indexing).
// Pass LSE: online (max,sumexp) in regs -> partials[row][chunk].
// Pass OUT: writes score - lse directly.
template <bool WRITE_OUT>
__global__ __launch_bounds__(256, 2) void gemm_wave_kernel(const unsigned short* __restrict__ t,
                                                           const unsigned short* __restrict__ neg,
                                                           float2* __restrict__ partials,
                                                           const float* __restrict__ lse,
                                                           float* __restrict__ out) {
    const int wave = threadIdx.x >> 6, lane = threadIdx.x & 63;
    const int l16  = lane & 15, q = lane >> 4;
    const int gw   = blockIdx.x * 4 + wave;
    const int rowgrp = gw & 15;          // 4 consecutive blocks share a chunk
    const int chunk  = gw >> 4;          // 0..127
    const int s0 = (chunk * NSTEPS) / NCH;
    const int s1 = ((chunk + 1) * NSTEPS) / NCH;
    const int rowbase = rowgrp * 64;

    // ---- A fragments: af[mf][ks], row = rowbase+mf*16+l16, k = ks*32+q*8  (16 x 16B, L2-hot)
    short8 af[4][4];
    #pragma unroll
    for (int mf = 0; mf < 4; ++mf)
        #pragma unroll
        for (int ks = 0; ks < 4; ++ks)
            af[mf][ks] = *(const short8*)&t[(size_t)(rowbase + mf * 16 + l16) * E_DIM + ks * 32 + q * 8];

    float mrun[4][4], srun[4][4], lsev[4][4];
    if (WRITE_OUT) {
        #pragma unroll
        for (int mf = 0; mf < 4; ++mf)
            #pragma unroll
            for (int r = 0; r < 4; ++r)
                lsev[mf][r] = lse[rowbase + mf * 16 + q * 4 + r];
    } else {
        #pragma unroll
        for (int mf = 0; mf < 4; ++mf)
            #pragma unroll
            for (int r = 0; r < 4; ++r) { mrun[mf][r] = -INFINITY; srun[mf][r] = 0.f; }
    }

    // ---- B loader: 8 x 16B into named reg set. bf[nf*4+ks] = cols cb+nf*16+l16, k ks*32+q*8
    auto LOADB = [&](short8 (&bf)[8], int s) {
        const int cb = s * 32;
        #pragma unroll
        for (int nf = 0; nf < 2; ++nf)
            #pragma unroll
            for (int ks = 0; ks < 4; ++ks)
                bf[nf * 4 + ks] = *(const short8*)&neg[(size_t)(cb + nf * 16 + l16) * E_DIM + ks * 32 + q * 8];
    };

    auto COMPUTE = [&](const short8 (&bf)[8], int s) {
        floatx4 acc[4][2];
        #pragma unroll
        for (int i = 0; i < 4; ++i)
            #pragma unroll
            for (int j = 0; j < 2; ++j) acc[i][j] = (floatx4){0, 0, 0, 0};
        #pragma unroll
        for (int ks = 0; ks < 4; ++ks)
            #pragma unroll
            for (int mf = 0; mf < 4; ++mf)
                #pragma unroll
                for (int nf = 0; nf < 2; ++nf)
                    acc[mf][nf] = __builtin_amdgcn_mfma_f32_16x16x32_bf16(af[mf][ks], bf[nf * 4 + ks], acc[mf][nf], 0, 0, 0);

        // acc[mf][nf][r]: row = rowbase+mf*16+q*4+r, col = s*32 + nf*16 + l16
        const int cb = s * 32;
        const bool v0 = (cb + l16) < V_COLS;
        const bool v1 = (cb + 16 + l16) < V_COLS;

        if (!WRITE_OUT) {
            #pragma unroll
            for (int mf = 0; mf < 4; ++mf)
                #pragma unroll
                for (int r = 0; r < 4; ++r) {
                    float a0 = v0 ? acc[mf][0][r] : -INFINITY;
                    float a1 = v1 ? acc[mf][1][r] : -INFINITY;
                    float nm = fmaxf(mrun[mf][r], fmaxf(a0, a1));
                    float sx = srun[mf][r] * __expf(mrun[mf][r] - nm);
                    if (v0) sx += __expf(a0 - nm);
                    if (v1) sx += __expf(a1 - nm);
                    mrun[mf][r] = nm; srun[mf][r] = sx;
                }
        } else {
            #pragma unroll
            for (int mf = 0; mf < 4; ++mf) {
                const size_t rowb = (size_t)(rowbase + mf * 16 + q * 4) * V_COLS;
                #pragma unroll
                for (int r = 0; r < 4; ++r) {
                    if (v0) out[rowb + (size_t)r * V_COLS + cb + l16]      = acc[mf][0][r] - lsev[mf][r];
                    if (v1) out[rowb + (size_t)r * V_COLS + cb + 16 + l16] = acc[mf][1][r] - lsev[mf][r];
                }
            }
        }
    };

    // ---- software-pipelined step loop, two named buffers, zero barriers
    short8 bA[8], bB[8];
    LOADB(bA, s0);
    int s = s0;
    for (;;) {
        if (s + 1 < s1) LOADB(bB, s + 1);   // prefetch issues before bA is consumed
        COMPUTE(bA, s);
        if (++s >= s1) break;
        if (s + 1 < s1) LOADB(bA, s + 1);
        COMPUTE(bB, s);
        if (++s >= s1) break;
    }

    if (!WRITE_OUT) {
        // merge across the 16 l16 lanes (same rows, different cols)
        #pragma unroll
        for (int mf = 0; mf < 4; ++mf)
            #pragma unroll
            for (int r = 0; r < 4; ++r) {
                float mm = mrun[mf][r], ss = srun[mf][r];
                #pragma unroll
                for (int d = 1; d < 16; d <<= 1) {
                    float mo = __shfl_xor(mm, d, 16);
                    float so = __shfl_xor(ss, d, 16);
                    float nm = fmaxf(mm, mo);
                    ss = ss * __expf(mm - nm) + so * __expf(mo - nm);
                    mm = nm;
                }
                if (l16 == 0)
                    partials[(size_t)(rowbase + mf * 16 + q * 4 + r) * NCH + chunk] = make_float2(mm, ss);
            }
    }
}

// ---------------------------------------------------------------- merge 128 partials/row -> lse[b]
__global__ __launch_bounds__(128) void merge_lse_kernel(const float2* __restrict__ partials,
                                                        float* __restrict__ lse) {
    int b = blockIdx.x, tid = threadIdx.x;
    float2 p = partials[(size_t)b * NCH + tid];
    float mm = p.x, ss = p.y;
    #pragma unroll
    for (int d = 1; d < 64; d <<= 1) {
        float mo = __shfl_xor(mm, d, 64);
        float so = __shfl_xor(ss, d, 64);
        float nm = fmaxf(mm, mo);
        ss = ss * __expf(mm - nm) + so * __expf(mo - nm);
        mm = nm;
    }
    __shared__ float m2[2], s2[2];
    if ((tid & 63) == 0) { m2[tid >> 6] = mm; s2[tid >> 6] = ss; }
    __syncthreads();
    if (tid == 0) {
        float nm = fmaxf(m2[0], m2[1]);
        float s  = s2[0] * __expf(m2[0] - nm) + s2[1] * __expf(m2[1] - nm);
        lse[b] = nm + __logf(s);
    }
}

// ---------------------------------------------------------------- launch
extern "C" void kernel_launch(void* const* d_in, const int* in_sizes, int n_in,
                              void* d_out, int out_size, void* d_ws, size_t ws_size,
                              hipStream_t stream) {
    const float* xs     = (const float*)d_in[0];
    const float* metric = (const float*)d_in[1];
    const float* EMB    = (const float*)d_in[2];
    const float* NEG    = (const float*)d_in[3];
    float* out = (float*)d_out;

    char* ws = (char*)d_ws;
    // layout: idx[1024] | t bf16[1024*128] | neg bf16[VPAD*128] | partials float2[1024*128] | lse[1024]
    int*            idx      = (int*)ws;                               // 4096 B
    unsigned short* t        = (unsigned short*)(ws + 4096);           // 262144 -> 266240
    unsigned short* neg16    = (unsigned short*)(ws + 266240);         // 12877824 -> 13144064
    float2*         partials = (float2*)(ws + 13144064);               // 1024*128*8 = 1048576 -> 14192640
    float*          lse      = (float*)(ws + 14192640);                // 4096 B

    {
        long n4 = (long)B_ROWS * V_COLS / 4;
        int blocks = (int)((n4 + 255) / 256);
        find_idx_kernel<<<blocks, 256, 0, stream>>>(xs, idx);
    }
    cvt_bf16_kernel<<<(N4P + 255) / 256, 256, 0, stream>>>(NEG, (ushort4*)neg16);
    compute_t_kernel<<<B_ROWS, E_DIM, 0, stream>>>(EMB, metric, idx, t);
    gemm_wave_kernel<false><<<512, 256, 0, stream>>>(t, neg16, partials, nullptr, nullptr);
    merge_lse_kernel<<<B_ROWS, 128, 0, stream>>>(partials, lse);
    gemm_wave_kernel<true><<<512, 256, 0, stream>>>(t, neg16, partials, lse, out);
}